// Round 7
// baseline (933.926 us; speedup 1.0000x reference)
//
#include <hip/hip_runtime.h>
#include <hip/hip_bf16.h>

// Problem constants
#define B_   4
#define T_   32
#define N_   370
#define E_   11840
#define E2_  12210          // E_ + N_ self loops
#define H_   64
#define G_   128            // B_*T_
#define GN_  47360          // G_*N_
#define BN_  1480           // B_*N_
#define NH_  23680          // N_*H_

__device__ __forceinline__ float gelu_f(float x){
  return 0.5f * x * (1.0f + erff(x * 0.7071067811865475f));
}
__device__ __forceinline__ float wsum64(float v){
  #pragma unroll
  for (int m = 32; m > 0; m >>= 1) v += __shfl_xor(v, m, 64);
  return v;
}
__device__ __forceinline__ float lrelu(float v){ return v > 0.f ? v : 0.2f * v; }

// ---------- edge preprocessing ----------
__global__ void k_deg_count(const int* __restrict__ ei, const float* __restrict__ ew,
                            float* __restrict__ deg, int* __restrict__ counts){
  int e = blockIdx.x * 256 + threadIdx.x;
  if (e >= E2_) return;
  int dst = (e < E_) ? ei[E_ + e] : (e - E_);
  float w = (e < E_) ? ew[e] : 1.0f;
  atomicAdd(&deg[dst], w);
  atomicAdd(&counts[dst], 1);
}

__global__ void k_gnorm(const int* __restrict__ ei, const float* __restrict__ ew,
                        const float* __restrict__ deg, float* __restrict__ gnorm){
  int e = blockIdx.x * 256 + threadIdx.x;
  if (e >= E2_) return;
  int s = (e < E_) ? ei[e] : (e - E_);
  int d = (e < E_) ? ei[E_ + e] : (e - E_);
  float w = (e < E_) ? ew[e] : 1.0f;
  float ds = deg[s] > 0.f ? rsqrtf(deg[s]) : 0.f;
  float dd = deg[d] > 0.f ? rsqrtf(deg[d]) : 0.f;
  gnorm[e] = ds * w * dd;
}

// wave-parallel exclusive scan over counts (one wave)
__global__ void k_scan(const int* __restrict__ counts, int* __restrict__ offs,
                       int* __restrict__ cursor){
  int lane = threadIdx.x;
  int run = 0;
  for (int c0 = 0; c0 < N_; c0 += 64){
    int n = c0 + lane;
    int v = (n < N_) ? counts[n] : 0;
    int s = v;
    #pragma unroll
    for (int m = 1; m < 64; m <<= 1){
      int t = __shfl_up(s, m, 64);
      if (lane >= m) s += t;
    }
    int excl = run + s - v;
    if (n < N_){ offs[n] = excl; cursor[n] = excl; }
    run += __shfl(s, 63, 64);
  }
  if (lane == 0) offs[N_] = run;
}

// stores PRE-SCALED source offset s*64 (element offset of row start)
__global__ void k_fill(const int* __restrict__ ei, const float* __restrict__ gnorm,
                       int* __restrict__ cursor, int* __restrict__ csr_soff,
                       float* __restrict__ csr_g){
  int e = blockIdx.x * 256 + threadIdx.x;
  if (e >= E2_) return;
  int s = (e < E_) ? ei[e] : (e - E_);
  int d = (e < E_) ? ei[E_ + e] : (e - E_);
  int pos = atomicAdd(&cursor[d], 1);
  csr_soff[pos] = s * 64;
  csr_g[pos] = gnorm[e];
}

// transpose temporal-conv weights: WT[l][(ci*5+k)*64 + ho] = W_t[l][ho*320+ci*5+k]
__global__ void k_wtr(const float* __restrict__ Wt, float* __restrict__ WT){
  int i = blockIdx.x * 256 + threadIdx.x;     // 3*20480 exact
  int l = i / 20480, rem = i - l * 20480;
  int ho = rem / 320, j = rem - ho * 320;
  WT[l * 20480 + j * 64 + ho] = Wt[i];
}

// rows x 64 @ 64 x 64 -> rows x 64 ; 64 rows/block, 4x4 register tile
__global__ __launch_bounds__(256) void k_rowgemm(const float* __restrict__ in,
                                                 const float* __restrict__ W,
                                                 float* __restrict__ outp){
  __shared__ float Ws[64 * 64];     // [k][col]
  __shared__ float rsT[64 * 68];    // [k][row], padded
  int tid = threadIdx.x;
  size_t r0 = (size_t)blockIdx.x * 64;
  for (int i = tid; i < 4096; i += 256) Ws[i] = W[i];
  for (int i = tid; i < 4096; i += 256){
    int r = i >> 6, k = i & 63;
    rsT[k * 68 + r] = in[(r0 + r) * 64 + k];
  }
  __syncthreads();
  int c0 = (tid & 15) * 4;
  int rr0 = (tid >> 4) * 4;
  float4 a0 = {0,0,0,0}, a1 = {0,0,0,0}, a2 = {0,0,0,0}, a3 = {0,0,0,0};
  #pragma unroll 4
  for (int k = 0; k < 64; ++k){
    float4 rv = *(const float4*)&rsT[k * 68 + rr0];
    float4 wv = *(const float4*)&Ws[k * 64 + c0];
    a0.x += rv.x*wv.x; a0.y += rv.x*wv.y; a0.z += rv.x*wv.z; a0.w += rv.x*wv.w;
    a1.x += rv.y*wv.x; a1.y += rv.y*wv.y; a1.z += rv.y*wv.z; a1.w += rv.y*wv.w;
    a2.x += rv.z*wv.x; a2.y += rv.z*wv.y; a2.z += rv.z*wv.z; a2.w += rv.z*wv.w;
    a3.x += rv.w*wv.x; a3.y += rv.w*wv.y; a3.z += rv.w*wv.z; a3.w += rv.w*wv.w;
  }
  *(float4*)&outp[(r0 + rr0 + 0) * 64 + c0] = a0;
  *(float4*)&outp[(r0 + rr0 + 1) * 64 + c0] = a1;
  *(float4*)&outp[(r0 + rr0 + 2) * 64 + c0] = a2;
  *(float4*)&outp[(r0 + rr0 + 3) * 64 + c0] = a3;
}

// GCN aggregate v2: one block per graph; whole hw[g] tile staged in LDS (94.7 KB).
// 16 waves sweep nodes; lane = channel; gathers hit LDS instead of L2.
__global__ __launch_bounds__(1024) void k_gcn_agg(const float* __restrict__ hw,
    const int* __restrict__ csr_soff, const int* __restrict__ offs,
    const float* __restrict__ csr_g, const float* __restrict__ b_gcn,
    float* __restrict__ gout){
  __shared__ float hwS[NH_];        // 370*64 floats = 94,720 B
  int g = blockIdx.x;
  int tid = threadIdx.x;
  const float* hwg = hw + (size_t)g * NH_;
  for (int i = tid; i < NH_; i += 1024) hwS[i] = hwg[i];
  __syncthreads();
  int wv = tid >> 6, c = tid & 63;
  float bv = b_gcn[c];
  for (int n = wv; n < N_; n += 16){
    int o0 = offs[n], o1 = offs[n + 1];
    float acc = 0.f;
    int p = o0;
    for (; p + 8 <= o1; p += 8){
      int s0 = csr_soff[p+0], s1 = csr_soff[p+1], s2 = csr_soff[p+2], s3 = csr_soff[p+3];
      int s4 = csr_soff[p+4], s5 = csr_soff[p+5], s6 = csr_soff[p+6], s7 = csr_soff[p+7];
      float w0 = csr_g[p+0], w1 = csr_g[p+1], w2 = csr_g[p+2], w3 = csr_g[p+3];
      float w4 = csr_g[p+4], w5 = csr_g[p+5], w6 = csr_g[p+6], w7 = csr_g[p+7];
      acc += w0*hwS[s0+c] + w1*hwS[s1+c] + w2*hwS[s2+c] + w3*hwS[s3+c]
           + w4*hwS[s4+c] + w5*hwS[s5+c] + w6*hwS[s6+c] + w7*hwS[s7+c];
    }
    for (; p < o1; ++p)
      acc += csr_g[p] * hwS[csr_soff[p] + c];
    gout[(size_t)g * NH_ + n * 64 + c] = gelu_f(acc + bv);
  }
}

// attention scores per (g,n,head)
__global__ void k_attn(const float* __restrict__ gh, const float* __restrict__ att_s,
                       const float* __restrict__ att_d, float* __restrict__ asrc,
                       float* __restrict__ adst){
  int idx = blockIdx.x * 256 + threadIdx.x;   // GN_*4 exact
  int head = idx & 3;
  int gn = idx >> 2;
  const float* row = gh + (size_t)gn * 64 + head * 16;
  float as = 0.f, ad = 0.f;
  #pragma unroll
  for (int d = 0; d < 16; ++d){
    float v = row[d];
    as += v * att_s[head * 16 + d];
    ad += v * att_d[head * 16 + d];
  }
  asrc[idx] = as;
  adst[idx] = ad;
}

// per (g,n,head): softmax max+denominator over incoming edges;
// writes UNNORMALIZED exp weights alpha[g][p][head] and invden[g][n][head]
__global__ void k_alpha(const float* __restrict__ asrc, const float* __restrict__ adst,
                        const int* __restrict__ csr_soff, const int* __restrict__ offs,
                        float* __restrict__ alpha, float* __restrict__ invden){
  int idx = blockIdx.x * 256 + threadIdx.x;   // (g*N+n)*4+head, GN_*4 exact
  int head = idx & 3;
  int gn = idx >> 2;
  int g = gn / N_, n = gn - g * N_;
  int o0 = offs[n], o1 = offs[n + 1];
  const float* as_g = asrc + (size_t)g * (N_ * 4);
  float adv = adst[idx];
  float m = -1e30f;
  int p = o0;
  for (; p + 4 <= o1; p += 4){
    int sa = csr_soff[p+0] >> 4, sb = csr_soff[p+1] >> 4;
    int sc = csr_soff[p+2] >> 4, sd = csr_soff[p+3] >> 4;
    float va = lrelu(as_g[sa + head] + adv);
    float vb = lrelu(as_g[sb + head] + adv);
    float vc = lrelu(as_g[sc + head] + adv);
    float vd = lrelu(as_g[sd + head] + adv);
    m = fmaxf(m, fmaxf(fmaxf(va, vb), fmaxf(vc, vd)));
  }
  for (; p < o1; ++p)
    m = fmaxf(m, lrelu(as_g[(csr_soff[p] >> 4) + head] + adv));
  float* al_g = alpha + (size_t)g * (E2_ * 4);
  float den = 0.f;
  p = o0;
  for (; p + 4 <= o1; p += 4){
    int sa = csr_soff[p+0] >> 4, sb = csr_soff[p+1] >> 4;
    int sc = csr_soff[p+2] >> 4, sd = csr_soff[p+3] >> 4;
    float ea = __expf(lrelu(as_g[sa + head] + adv) - m);
    float eb = __expf(lrelu(as_g[sb + head] + adv) - m);
    float ec = __expf(lrelu(as_g[sc + head] + adv) - m);
    float ed = __expf(lrelu(as_g[sd + head] + adv) - m);
    den += ea + eb + ec + ed;
    al_g[(p+0)*4 + head] = ea;
    al_g[(p+1)*4 + head] = eb;
    al_g[(p+2)*4 + head] = ec;
    al_g[(p+3)*4 + head] = ed;
  }
  for (; p < o1; ++p){
    float ex = __expf(lrelu(as_g[(csr_soff[p] >> 4) + head] + adv) - m);
    den += ex;
    al_g[p*4 + head] = ex;
  }
  invden[idx] = 1.f / den;
}

// GAT aggregate v2: one block per graph; gh[g] tile staged in LDS; epilogue
// bias + residual + LayerNorm in-place on h
__global__ __launch_bounds__(1024) void k_gat_agg(const float* __restrict__ gh,
    const float* __restrict__ alpha, const float* __restrict__ invden,
    const int* __restrict__ csr_soff, const int* __restrict__ offs,
    const float* __restrict__ b_gat, const float* __restrict__ ln_g,
    const float* __restrict__ ln_b, float* __restrict__ h){
  __shared__ float ghS[NH_];        // 94,720 B
  int g = blockIdx.x;
  int tid = threadIdx.x;
  const float* ghg = gh + (size_t)g * NH_;
  for (int i = tid; i < NH_; i += 1024) ghS[i] = ghg[i];
  __syncthreads();
  int wv = tid >> 6, c = tid & 63;
  int head = c >> 4;
  const float* al_g = alpha + (size_t)g * (E2_ * 4);
  float bgv = b_gat[c], lgv = ln_g[c], lbv = ln_b[c];
  for (int n = wv; n < N_; n += 16){
    int o0 = offs[n], o1 = offs[n + 1];
    float acc = 0.f;
    int p = o0;
    for (; p + 8 <= o1; p += 8){
      int s0 = csr_soff[p+0], s1 = csr_soff[p+1], s2 = csr_soff[p+2], s3 = csr_soff[p+3];
      int s4 = csr_soff[p+4], s5 = csr_soff[p+5], s6 = csr_soff[p+6], s7 = csr_soff[p+7];
      float a0 = al_g[(p+0)*4+head], a1 = al_g[(p+1)*4+head];
      float a2 = al_g[(p+2)*4+head], a3 = al_g[(p+3)*4+head];
      float a4 = al_g[(p+4)*4+head], a5 = al_g[(p+5)*4+head];
      float a6 = al_g[(p+6)*4+head], a7 = al_g[(p+7)*4+head];
      acc += a0*ghS[s0+c] + a1*ghS[s1+c] + a2*ghS[s2+c] + a3*ghS[s3+c]
           + a4*ghS[s4+c] + a5*ghS[s5+c] + a6*ghS[s6+c] + a7*ghS[s7+c];
    }
    for (; p < o1; ++p)
      acc += al_g[p*4+head] * ghS[csr_soff[p] + c];
    float outv = acc * invden[((size_t)g * N_ + n) * 4 + head] + bgv;
    size_t hidx = ((size_t)g * N_ + n) * 64 + c;
    float r = outv + h[hidx];
    float mu = wsum64(r) * (1.f / 64.f);
    float d = r - mu;
    float var = wsum64(d * d) * (1.f / 64.f);
    h[hidx] = d * rsqrtf(var + 1e-5f) * lgv + lbv;
  }
}

// Fused temporal: transpose + 3 conv layers + reshape. 2 bn per block,
// 2 waves per bn (t0 = 0/16), 16 t per lane -> 32 FMA per W load.
__global__ __launch_bounds__(256) void k_tfuse(const float* __restrict__ h,
    const float* __restrict__ WT, const float* __restrict__ bt,
    float* __restrict__ z){
  __shared__ float tiles[2][2][64 * 36];
  int tid = threadIdx.x;
  int wv = tid >> 6, lane = tid & 63;
  int bnl = wv >> 1;
  int t0 = (wv & 1) * 16;
  int bn = blockIdx.x * 2 + bnl;
  int b = bn / N_, n = bn - b * N_;
  for (int i = tid; i < 2 * 2 * 2304; i += 256) ((float*)tiles)[i] = 0.f;
  __syncthreads();
  {
    float* xa = tiles[bnl][0];
    for (int i = (wv & 1) * 64 + lane; i < 2048; i += 128){
      int t = i >> 6, ch = i & 63;
      xa[ch * 36 + 2 + t] = h[((size_t)(b * T_ + t) * N_ + n) * 64 + ch];
    }
  }
  __syncthreads();
  int ho = lane;
  #pragma unroll
  for (int l = 0; l < 3; ++l){
    float* cur = tiles[bnl][l & 1];
    float* nxt = tiles[bnl][(l & 1) ^ 1];
    const float* wl = WT + l * 20480 + ho;
    float bv = bt[l * 64 + ho];
    float acc[16];
    #pragma unroll
    for (int r = 0; r < 16; ++r) acc[r] = bv;
    for (int ci = 0; ci < 64; ++ci){
      const float* xr = &cur[ci * 36 + t0];   // xr[q] = x[ci][t0+q-2], q=0..19
      float4 x0 = *(const float4*)&xr[0];
      float4 x1 = *(const float4*)&xr[4];
      float4 x2 = *(const float4*)&xr[8];
      float4 x3 = *(const float4*)&xr[12];
      float4 x4 = *(const float4*)&xr[16];
      float xw[20] = {x0.x,x0.y,x0.z,x0.w, x1.x,x1.y,x1.z,x1.w,
                      x2.x,x2.y,x2.z,x2.w, x3.x,x3.y,x3.z,x3.w,
                      x4.x,x4.y,x4.z,x4.w};
      const float* wp = wl + ci * 320;        // (ci*5+k)*64 + ho
      #pragma unroll
      for (int k = 0; k < 5; ++k){
        float w = wp[k * 64];
        #pragma unroll
        for (int r = 0; r < 16; ++r) acc[r] += xw[r + k] * w;
      }
    }
    #pragma unroll
    for (int r = 0; r < 16; ++r){
      int ti = t0 + r;
      nxt[ho * 36 + 2 + ti] = gelu_f(acc[r]) + cur[ho * 36 + 2 + ti];
    }
    __syncthreads();
  }
  float* fin = tiles[bnl][1];   // l=0 ->[1], l=1 ->[0], l=2 ->[1]
  for (int i = (wv & 1) * 64 + lane; i < 2048; i += 128){
    int t = i >> 6, ch = i & 63;
    z[(size_t)(b * T_ + t) * NH_ + n * 64 + ch] = fin[ch * 36 + 2 + t];
  }
}

// MLP layer 1: grid (4 rowgroups = b, 128 kchunks of 185);
// each thread: 8 rows x 4 cols (32 FMA per W1 float4 load)
__global__ __launch_bounds__(256) void k_mlp1(const float* __restrict__ z,
    const float* __restrict__ W1, float* __restrict__ y1){
  __shared__ float zs[185 * 36];    // [j][r], r=0..31, stride 36
  int b = blockIdx.x;               // 0..3
  int kc = blockIdx.y;              // 0..127
  int base = kc * 185;
  int tid = threadIdx.x;
  for (int i = tid; i < 185 * 32; i += 256){
    int r = i / 185, j = i - r * 185;
    zs[j * 36 + r] = z[(size_t)(b * T_ + r) * NH_ + base + j];
  }
  __syncthreads();
  int r0 = (tid >> 6) * 8;
  int c0 = (tid & 63) * 4;
  float4 acc[8];
  #pragma unroll
  for (int r = 0; r < 8; ++r) acc[r] = (float4){0,0,0,0};
  const float* wbase = W1 + (size_t)base * 256 + c0;
  #pragma unroll 4
  for (int j = 0; j < 185; ++j){
    float4 wv = *(const float4*)&wbase[(size_t)j * 256];
    float4 za = *(const float4*)&zs[j * 36 + r0];
    float4 zb = *(const float4*)&zs[j * 36 + r0 + 4];
    acc[0].x += za.x*wv.x; acc[0].y += za.x*wv.y; acc[0].z += za.x*wv.z; acc[0].w += za.x*wv.w;
    acc[1].x += za.y*wv.x; acc[1].y += za.y*wv.y; acc[1].z += za.y*wv.z; acc[1].w += za.y*wv.w;
    acc[2].x += za.z*wv.x; acc[2].y += za.z*wv.y; acc[2].z += za.z*wv.z; acc[2].w += za.z*wv.w;
    acc[3].x += za.w*wv.x; acc[3].y += za.w*wv.y; acc[3].z += za.w*wv.z; acc[3].w += za.w*wv.w;
    acc[4].x += zb.x*wv.x; acc[4].y += zb.x*wv.y; acc[4].z += zb.x*wv.z; acc[4].w += zb.x*wv.w;
    acc[5].x += zb.y*wv.x; acc[5].y += zb.y*wv.y; acc[5].z += zb.y*wv.z; acc[5].w += zb.y*wv.w;
    acc[6].x += zb.z*wv.x; acc[6].y += zb.z*wv.y; acc[6].z += zb.z*wv.z; acc[6].w += zb.z*wv.w;
    acc[7].x += zb.w*wv.x; acc[7].y += zb.w*wv.y; acc[7].z += zb.w*wv.z; acc[7].w += zb.w*wv.w;
  }
  #pragma unroll
  for (int rr = 0; rr < 8; ++rr){
    int row = b * T_ + r0 + rr;
    float* yp = &y1[(size_t)row * 256 + c0];
    atomicAdd(&yp[0], acc[rr].x);
    atomicAdd(&yp[1], acc[rr].y);
    atomicAdd(&yp[2], acc[rr].z);
    atomicAdd(&yp[3], acc[rr].w);
  }
}

// MLP layer 2: out[128,64] = gelu(y1+b1) @ W2 + b2
__global__ __launch_bounds__(64) void k_mlp2(const float* __restrict__ y1,
    const float* __restrict__ b1, const float* __restrict__ W2,
    const float* __restrict__ b2, float* __restrict__ outp){
  __shared__ float a[256];
  int row = blockIdx.x, tid = threadIdx.x;
  for (int i = tid; i < 256; i += 64) a[i] = gelu_f(y1[(size_t)row * 256 + i] + b1[i]);
  __syncthreads();
  float acc = b2[tid];
  for (int i = 0; i < 256; ++i) acc += a[i] * W2[i * 64 + tid];
  outp[row * 64 + tid] = acc;
}

extern "C" void kernel_launch(void* const* d_in, const int* in_sizes, int n_in,
                              void* d_out, int out_size, void* d_ws, size_t ws_size,
                              hipStream_t stream){
  const float* x     = (const float*)d_in[0];
  const int*   ei    = (const int*)  d_in[1];
  const float* ew    = (const float*)d_in[2];
  const float* W_gcn = (const float*)d_in[3];
  const float* b_gcn = (const float*)d_in[4];
  const float* W_gat = (const float*)d_in[5];
  const float* att_s = (const float*)d_in[6];
  const float* att_d = (const float*)d_in[7];
  const float* b_gat = (const float*)d_in[8];
  const float* W_t   = (const float*)d_in[9];
  const float* b_t   = (const float*)d_in[10];
  const float* ln_g  = (const float*)d_in[11];
  const float* ln_b  = (const float*)d_in[12];
  const float* W1    = (const float*)d_in[13];
  const float* b1    = (const float*)d_in[14];
  const float* W2    = (const float*)d_in[15];
  const float* b2    = (const float*)d_in[16];
  float* outp = (float*)d_out;

  float* F = (float*)d_ws;
  size_t off = 0;
  float* deg    = F + off; off += 512;
  float* gnorm  = F + off; off += 12288;
  float* csr_g  = F + off; off += 12288;
  float* asrc   = F + off; off += 189440;
  float* adst   = F + off; off += 189440;
  float* invden = F + off; off += 189440;
  float* y1     = F + off; off += 32768;
  float* WT     = F + off; off += 61440;     // transposed temporal weights
  float* h      = F + off; off += 3031040;
  float* bufB   = F + off; off += 3031040;   // hw
  float* bufC   = F + off; off += 3031040;   // g
  float* bufD   = F + off; off += 3031040;   // gh / z
  float* alpha  = F + off; off += (size_t)G_ * E2_ * 4;   // 6,251,520
  int* I        = (int*)(F + off);
  int* counts   = I;
  int* offs     = I + 512;
  int* cursor   = I + 1024;
  int* csr_soff = I + 1536;                  // E2_ entries

  hipMemsetAsync(deg, 0, 512 * sizeof(float), stream);
  hipMemsetAsync(counts, 0, 512 * sizeof(int), stream);
  hipMemsetAsync(y1, 0, 32768 * sizeof(float), stream);

  k_deg_count<<<48, 256, 0, stream>>>(ei, ew, deg, counts);
  k_gnorm<<<48, 256, 0, stream>>>(ei, ew, deg, gnorm);
  k_scan<<<1, 64, 0, stream>>>(counts, offs, cursor);
  k_fill<<<48, 256, 0, stream>>>(ei, gnorm, cursor, csr_soff, csr_g);
  k_wtr<<<240, 256, 0, stream>>>(W_t, WT);
  hipMemcpyAsync(h, x, (size_t)GN_ * 64 * sizeof(float), hipMemcpyDeviceToDevice, stream);

  for (int l = 0; l < 3; ++l){
    k_rowgemm<<<740, 256, 0, stream>>>(h, W_gcn + l * 4096, bufB);
    k_gcn_agg<<<G_, 1024, 0, stream>>>(bufB, csr_soff, offs, csr_g, b_gcn + l * 64, bufC);
    k_rowgemm<<<740, 256, 0, stream>>>(bufC, W_gat + l * 4096, bufD);
    k_attn<<<740, 256, 0, stream>>>(bufD, att_s + l * 64, att_d + l * 64, asrc, adst);
    k_alpha<<<740, 256, 0, stream>>>(asrc, adst, csr_soff, offs, alpha, invden);
    k_gat_agg<<<G_, 1024, 0, stream>>>(bufD, alpha, invden, csr_soff, offs,
                                       b_gat + l * 64, ln_g + l * 64, ln_b + l * 64, h);
  }

  k_tfuse<<<740, 256, 0, stream>>>(h, WT, b_t, bufD);

  dim3 g1(4, 128);
  k_mlp1<<<g1, 256, 0, stream>>>(bufD, W1, y1);
  k_mlp2<<<128, 64, 0, stream>>>(y1, b1, W2, b2, outp);
}

// Round 8
// 827.674 us; speedup vs baseline: 1.1284x; 1.1284x over previous
//
#include <hip/hip_runtime.h>
#include <hip/hip_bf16.h>

// Problem constants
#define B_   4
#define T_   32
#define N_   370
#define E_   11840
#define E2_  12210          // E_ + N_ self loops
#define H_   64
#define G_   128            // B_*T_
#define GN_  47360          // G_*N_
#define BN_  1480           // B_*N_
#define NH_  23680          // N_*H_

__device__ __forceinline__ float gelu_f(float x){
  return 0.5f * x * (1.0f + erff(x * 0.7071067811865475f));
}
__device__ __forceinline__ float wsum64(float v){
  #pragma unroll
  for (int m = 32; m > 0; m >>= 1) v += __shfl_xor(v, m, 64);
  return v;
}
__device__ __forceinline__ float lrelu(float v){ return v > 0.f ? v : 0.2f * v; }

// ---------- edge preprocessing ----------
__global__ void k_deg_count(const int* __restrict__ ei, const float* __restrict__ ew,
                            float* __restrict__ deg, int* __restrict__ counts){
  int e = blockIdx.x * 256 + threadIdx.x;
  if (e >= E2_) return;
  int dst = (e < E_) ? ei[E_ + e] : (e - E_);
  float w = (e < E_) ? ew[e] : 1.0f;
  atomicAdd(&deg[dst], w);
  atomicAdd(&counts[dst], 1);
}

__global__ void k_gnorm(const int* __restrict__ ei, const float* __restrict__ ew,
                        const float* __restrict__ deg, float* __restrict__ gnorm){
  int e = blockIdx.x * 256 + threadIdx.x;
  if (e >= E2_) return;
  int s = (e < E_) ? ei[e] : (e - E_);
  int d = (e < E_) ? ei[E_ + e] : (e - E_);
  float w = (e < E_) ? ew[e] : 1.0f;
  float ds = deg[s] > 0.f ? rsqrtf(deg[s]) : 0.f;
  float dd = deg[d] > 0.f ? rsqrtf(deg[d]) : 0.f;
  gnorm[e] = ds * w * dd;
}

// wave-parallel exclusive scan over counts (one wave)
__global__ void k_scan(const int* __restrict__ counts, int* __restrict__ offs,
                       int* __restrict__ cursor){
  int lane = threadIdx.x;
  int run = 0;
  for (int c0 = 0; c0 < N_; c0 += 64){
    int n = c0 + lane;
    int v = (n < N_) ? counts[n] : 0;
    int s = v;
    #pragma unroll
    for (int m = 1; m < 64; m <<= 1){
      int t = __shfl_up(s, m, 64);
      if (lane >= m) s += t;
    }
    int excl = run + s - v;
    if (n < N_){ offs[n] = excl; cursor[n] = excl; }
    run += __shfl(s, 63, 64);
  }
  if (lane == 0) offs[N_] = run;
}

// stores PRE-SCALED source offset s*64 (element offset of row start)
__global__ void k_fill(const int* __restrict__ ei, const float* __restrict__ gnorm,
                       int* __restrict__ cursor, int* __restrict__ csr_soff,
                       float* __restrict__ csr_g){
  int e = blockIdx.x * 256 + threadIdx.x;
  if (e >= E2_) return;
  int s = (e < E_) ? ei[e] : (e - E_);
  int d = (e < E_) ? ei[E_ + e] : (e - E_);
  int pos = atomicAdd(&cursor[d], 1);
  csr_soff[pos] = s * 64;
  csr_g[pos] = gnorm[e];
}

// transpose temporal-conv weights: WT[l][(ci*5+k)*64 + ho] = W_t[l][ho*320+ci*5+k]
__global__ void k_wtr(const float* __restrict__ Wt, float* __restrict__ WT){
  int i = blockIdx.x * 256 + threadIdx.x;     // 3*20480 exact
  int l = i / 20480, rem = i - l * 20480;
  int ho = rem / 320, j = rem - ho * 320;
  WT[l * 20480 + j * 64 + ho] = Wt[i];
}

// rows x 64 @ 64 x 64 -> rows x 64 ; 128 rows/block, 8x4 register tile
__global__ __launch_bounds__(256) void k_rowgemm(const float* __restrict__ in,
                                                 const float* __restrict__ W,
                                                 float* __restrict__ outp){
  __shared__ float Ws[64 * 64];      // [k][col]
  __shared__ float rsT[64 * 132];    // [k][row], stride 132 (4-mod-32 pad)
  int tid = threadIdx.x;
  size_t r0 = (size_t)blockIdx.x * 128;
  for (int i = tid; i < 4096; i += 256) Ws[i] = W[i];
  for (int i = tid; i < 8192; i += 256){
    int r = i >> 6, k = i & 63;
    rsT[k * 132 + r] = in[(r0 + r) * 64 + k];
  }
  __syncthreads();
  int c0 = (tid & 15) * 4;
  int rr0 = (tid >> 4) * 8;
  float4 acc[8];
  #pragma unroll
  for (int q = 0; q < 8; ++q) acc[q] = (float4){0,0,0,0};
  #pragma unroll 2
  for (int k = 0; k < 64; ++k){
    float4 ra = *(const float4*)&rsT[k * 132 + rr0];
    float4 rb = *(const float4*)&rsT[k * 132 + rr0 + 4];
    float4 wv = *(const float4*)&Ws[k * 64 + c0];
    float rv[8] = {ra.x, ra.y, ra.z, ra.w, rb.x, rb.y, rb.z, rb.w};
    #pragma unroll
    for (int q = 0; q < 8; ++q){
      acc[q].x += rv[q]*wv.x; acc[q].y += rv[q]*wv.y;
      acc[q].z += rv[q]*wv.z; acc[q].w += rv[q]*wv.w;
    }
  }
  #pragma unroll
  for (int q = 0; q < 8; ++q)
    *(float4*)&outp[(r0 + rr0 + q) * 64 + c0] = acc[q];
}

// GCN aggregate: 4 (g,n) per block, one wave each; edge loop unrolled x16
__global__ __launch_bounds__(256) void k_gcn_agg(const float* __restrict__ hw,
    const int* __restrict__ csr_soff, const int* __restrict__ offs,
    const float* __restrict__ csr_g, const float* __restrict__ b_gcn,
    float* __restrict__ gout){
  int gn = blockIdx.x * 4 + (threadIdx.x >> 6);
  int c = threadIdx.x & 63;
  int g = gn / N_, n = gn - g * N_;
  int o0 = offs[n], o1 = offs[n + 1];
  const float* hwg = hw + (size_t)g * NH_;
  float acc = 0.f;
  int p = o0;
  for (; p + 16 <= o1; p += 16){
    int s[16]; float w[16]; float v[16];
    #pragma unroll
    for (int q = 0; q < 16; ++q){ s[q] = csr_soff[p+q]; w[q] = csr_g[p+q]; }
    #pragma unroll
    for (int q = 0; q < 16; ++q) v[q] = hwg[s[q] + c];
    #pragma unroll
    for (int q = 0; q < 16; ++q) acc += w[q] * v[q];
  }
  for (; p < o1; ++p)
    acc += csr_g[p] * hwg[csr_soff[p] + c];
  acc += b_gcn[c];
  gout[(size_t)gn * 64 + c] = gelu_f(acc);
}

// attention scores per (g,n,head)
__global__ void k_attn(const float* __restrict__ gh, const float* __restrict__ att_s,
                       const float* __restrict__ att_d, float* __restrict__ asrc,
                       float* __restrict__ adst){
  int idx = blockIdx.x * 256 + threadIdx.x;   // GN_*4 exact
  int head = idx & 3;
  int gn = idx >> 2;
  const float* row = gh + (size_t)gn * 64 + head * 16;
  float as = 0.f, ad = 0.f;
  #pragma unroll
  for (int d = 0; d < 16; ++d){
    float v = row[d];
    as += v * att_s[head * 16 + d];
    ad += v * att_d[head * 16 + d];
  }
  asrc[idx] = as;
  adst[idx] = ad;
}

// per (g,n,head): softmax max+denominator over incoming edges;
// writes UNNORMALIZED exp weights alpha[g][p][head] and invden[g][n][head]
__global__ void k_alpha(const float* __restrict__ asrc, const float* __restrict__ adst,
                        const int* __restrict__ csr_soff, const int* __restrict__ offs,
                        float* __restrict__ alpha, float* __restrict__ invden){
  int idx = blockIdx.x * 256 + threadIdx.x;   // (g*N+n)*4+head, GN_*4 exact
  int head = idx & 3;
  int gn = idx >> 2;
  int g = gn / N_, n = gn - g * N_;
  int o0 = offs[n], o1 = offs[n + 1];
  const float* as_g = asrc + (size_t)g * (N_ * 4);
  float adv = adst[idx];
  float m = -1e30f;
  int p = o0;
  for (; p + 4 <= o1; p += 4){
    int sa = csr_soff[p+0] >> 4, sb = csr_soff[p+1] >> 4;
    int sc = csr_soff[p+2] >> 4, sd = csr_soff[p+3] >> 4;
    float va = lrelu(as_g[sa + head] + adv);
    float vb = lrelu(as_g[sb + head] + adv);
    float vc = lrelu(as_g[sc + head] + adv);
    float vd = lrelu(as_g[sd + head] + adv);
    m = fmaxf(m, fmaxf(fmaxf(va, vb), fmaxf(vc, vd)));
  }
  for (; p < o1; ++p)
    m = fmaxf(m, lrelu(as_g[(csr_soff[p] >> 4) + head] + adv));
  float* al_g = alpha + (size_t)g * (E2_ * 4);
  float den = 0.f;
  p = o0;
  for (; p + 4 <= o1; p += 4){
    int sa = csr_soff[p+0] >> 4, sb = csr_soff[p+1] >> 4;
    int sc = csr_soff[p+2] >> 4, sd = csr_soff[p+3] >> 4;
    float ea = __expf(lrelu(as_g[sa + head] + adv) - m);
    float eb = __expf(lrelu(as_g[sb + head] + adv) - m);
    float ec = __expf(lrelu(as_g[sc + head] + adv) - m);
    float ed = __expf(lrelu(as_g[sd + head] + adv) - m);
    den += ea + eb + ec + ed;
    al_g[(p+0)*4 + head] = ea;
    al_g[(p+1)*4 + head] = eb;
    al_g[(p+2)*4 + head] = ec;
    al_g[(p+3)*4 + head] = ed;
  }
  for (; p < o1; ++p){
    float ex = __expf(lrelu(as_g[(csr_soff[p] >> 4) + head] + adv) - m);
    den += ex;
    al_g[p*4 + head] = ex;
  }
  invden[idx] = 1.f / den;
}

// GAT aggregate (single pass, precomputed alpha) + bias + residual + LayerNorm
__global__ __launch_bounds__(256) void k_gat_agg(const float* __restrict__ gh,
    const float* __restrict__ alpha, const float* __restrict__ invden,
    const int* __restrict__ csr_soff, const int* __restrict__ offs,
    const float* __restrict__ b_gat, const float* __restrict__ ln_g,
    const float* __restrict__ ln_b, float* __restrict__ h){
  int gn = blockIdx.x * 4 + (threadIdx.x >> 6);
  int c = threadIdx.x & 63;
  int g = gn / N_, n = gn - g * N_;
  int head = c >> 4;
  int o0 = offs[n], o1 = offs[n + 1];
  const float* gh_g = gh + (size_t)g * NH_;
  const float* al_g = alpha + (size_t)g * (E2_ * 4);
  size_t hidx = (size_t)gn * 64 + c;
  float hres = h[hidx];
  float acc = 0.f;
  int p = o0;
  for (; p + 16 <= o1; p += 16){
    int s[16]; float a[16]; float v[16];
    #pragma unroll
    for (int q = 0; q < 16; ++q){ s[q] = csr_soff[p+q]; a[q] = al_g[(p+q)*4+head]; }
    #pragma unroll
    for (int q = 0; q < 16; ++q) v[q] = gh_g[s[q] + c];
    #pragma unroll
    for (int q = 0; q < 16; ++q) acc += a[q] * v[q];
  }
  for (; p < o1; ++p)
    acc += al_g[p*4+head] * gh_g[csr_soff[p] + c];
  float outv = acc * invden[gn * 4 + head] + b_gat[c];
  float r = outv + hres;
  float mu = wsum64(r) * (1.f / 64.f);
  float d = r - mu;
  float var = wsum64(d * d) * (1.f / 64.f);
  h[hidx] = d * rsqrtf(var + 1e-5f) * ln_g[c] + ln_b[c];
}

// Fused temporal: transpose + 3 conv layers + reshape. 2 bn per block,
// 2 waves per bn (t0 = 0/16), 16 t per lane, SINGLE buffer per bn
// (in-place writeback after barrier) -> LDS 18.4 KB.
__global__ __launch_bounds__(256) void k_tfuse(const float* __restrict__ h,
    const float* __restrict__ WT, const float* __restrict__ bt,
    float* __restrict__ z){
  __shared__ float tiles[2][64 * 36];
  int tid = threadIdx.x;
  int wv = tid >> 6, lane = tid & 63;
  int bnl = wv >> 1;
  int t0 = (wv & 1) * 16;
  int bn = blockIdx.x * 2 + bnl;
  int b = bn / N_, n = bn - b * N_;
  for (int i = tid; i < 2 * 2304; i += 256) ((float*)tiles)[i] = 0.f;
  __syncthreads();
  {
    float* xa = tiles[bnl];
    for (int i = (wv & 1) * 64 + lane; i < 2048; i += 128){
      int t = i >> 6, ch = i & 63;
      xa[ch * 36 + 2 + t] = h[((size_t)(b * T_ + t) * N_ + n) * 64 + ch];
    }
  }
  __syncthreads();
  int ho = lane;
  float* cur = tiles[bnl];
  #pragma unroll
  for (int l = 0; l < 3; ++l){
    const float* wl = WT + l * 20480 + ho;
    float bv = bt[l * 64 + ho];
    float acc[16];
    #pragma unroll
    for (int r = 0; r < 16; ++r) acc[r] = bv;
    for (int ci = 0; ci < 64; ++ci){
      const float* xr = &cur[ci * 36 + t0];   // xr[q] = x[ci][t0+q-2], q=0..19
      float4 x0 = *(const float4*)&xr[0];
      float4 x1 = *(const float4*)&xr[4];
      float4 x2 = *(const float4*)&xr[8];
      float4 x3 = *(const float4*)&xr[12];
      float4 x4 = *(const float4*)&xr[16];
      float xw[20] = {x0.x,x0.y,x0.z,x0.w, x1.x,x1.y,x1.z,x1.w,
                      x2.x,x2.y,x2.z,x2.w, x3.x,x3.y,x3.z,x3.w,
                      x4.x,x4.y,x4.z,x4.w};
      const float* wp = wl + ci * 320;        // (ci*5+k)*64 + ho
      #pragma unroll
      for (int k = 0; k < 5; ++k){
        float w = wp[k * 64];
        #pragma unroll
        for (int r = 0; r < 16; ++r) acc[r] += xw[r + k] * w;
      }
    }
    __syncthreads();     // all reads of cur done
    #pragma unroll
    for (int r = 0; r < 16; ++r){
      int ti = t0 + r;
      cur[ho * 36 + 2 + ti] = gelu_f(acc[r]) + cur[ho * 36 + 2 + ti];
    }
    __syncthreads();     // writes visible before next layer reads
  }
  for (int i = (wv & 1) * 64 + lane; i < 2048; i += 128){
    int t = i >> 6, ch = i & 63;
    z[(size_t)(b * T_ + t) * NH_ + n * 64 + ch] = cur[ch * 36 + 2 + t];
  }
}

// MLP layer 1: grid (4 rowgroups = b, 128 kchunks of 185);
// each thread: 8 rows x 4 cols (32 FMA per W1 float4 load)
__global__ __launch_bounds__(256) void k_mlp1(const float* __restrict__ z,
    const float* __restrict__ W1, float* __restrict__ y1){
  __shared__ float zs[185 * 36];    // [j][r], r=0..31, stride 36
  int b = blockIdx.x;               // 0..3
  int kc = blockIdx.y;              // 0..127
  int base = kc * 185;
  int tid = threadIdx.x;
  for (int i = tid; i < 185 * 32; i += 256){
    int r = i / 185, j = i - r * 185;
    zs[j * 36 + r] = z[(size_t)(b * T_ + r) * NH_ + base + j];
  }
  __syncthreads();
  int r0 = (tid >> 6) * 8;
  int c0 = (tid & 63) * 4;
  float4 acc[8];
  #pragma unroll
  for (int r = 0; r < 8; ++r) acc[r] = (float4){0,0,0,0};
  const float* wbase = W1 + (size_t)base * 256 + c0;
  #pragma unroll 4
  for (int j = 0; j < 185; ++j){
    float4 wv = *(const float4*)&wbase[(size_t)j * 256];
    float4 za = *(const float4*)&zs[j * 36 + r0];
    float4 zb = *(const float4*)&zs[j * 36 + r0 + 4];
    float zv[8] = {za.x, za.y, za.z, za.w, zb.x, zb.y, zb.z, zb.w};
    #pragma unroll
    for (int q = 0; q < 8; ++q){
      acc[q].x += zv[q]*wv.x; acc[q].y += zv[q]*wv.y;
      acc[q].z += zv[q]*wv.z; acc[q].w += zv[q]*wv.w;
    }
  }
  #pragma unroll
  for (int rr = 0; rr < 8; ++rr){
    int row = b * T_ + r0 + rr;
    float* yp = &y1[(size_t)row * 256 + c0];
    atomicAdd(&yp[0], acc[rr].x);
    atomicAdd(&yp[1], acc[rr].y);
    atomicAdd(&yp[2], acc[rr].z);
    atomicAdd(&yp[3], acc[rr].w);
  }
}

// MLP layer 2: out[128,64] = gelu(y1+b1) @ W2 + b2
__global__ __launch_bounds__(64) void k_mlp2(const float* __restrict__ y1,
    const float* __restrict__ b1, const float* __restrict__ W2,
    const float* __restrict__ b2, float* __restrict__ outp){
  __shared__ float a[256];
  int row = blockIdx.x, tid = threadIdx.x;
  for (int i = tid; i < 256; i += 64) a[i] = gelu_f(y1[(size_t)row * 256 + i] + b1[i]);
  __syncthreads();
  float acc = b2[tid];
  for (int i = 0; i < 256; ++i) acc += a[i] * W2[i * 64 + tid];
  outp[row * 64 + tid] = acc;
}

extern "C" void kernel_launch(void* const* d_in, const int* in_sizes, int n_in,
                              void* d_out, int out_size, void* d_ws, size_t ws_size,
                              hipStream_t stream){
  const float* x     = (const float*)d_in[0];
  const int*   ei    = (const int*)  d_in[1];
  const float* ew    = (const float*)d_in[2];
  const float* W_gcn = (const float*)d_in[3];
  const float* b_gcn = (const float*)d_in[4];
  const float* W_gat = (const float*)d_in[5];
  const float* att_s = (const float*)d_in[6];
  const float* att_d = (const float*)d_in[7];
  const float* b_gat = (const float*)d_in[8];
  const float* W_t   = (const float*)d_in[9];
  const float* b_t   = (const float*)d_in[10];
  const float* ln_g  = (const float*)d_in[11];
  const float* ln_b  = (const float*)d_in[12];
  const float* W1    = (const float*)d_in[13];
  const float* b1    = (const float*)d_in[14];
  const float* W2    = (const float*)d_in[15];
  const float* b2    = (const float*)d_in[16];
  float* outp = (float*)d_out;

  float* F = (float*)d_ws;
  size_t off = 0;
  float* deg    = F + off; off += 512;
  float* gnorm  = F + off; off += 12288;
  float* csr_g  = F + off; off += 12288;
  float* asrc   = F + off; off += 189440;
  float* adst   = F + off; off += 189440;
  float* invden = F + off; off += 189440;
  float* y1     = F + off; off += 32768;
  float* WT     = F + off; off += 61440;     // transposed temporal weights
  float* h      = F + off; off += 3031040;
  float* bufB   = F + off; off += 3031040;   // hw
  float* bufC   = F + off; off += 3031040;   // g
  float* bufD   = F + off; off += 3031040;   // gh / z
  float* alpha  = F + off; off += (size_t)G_ * E2_ * 4;   // 6,251,520
  int* I        = (int*)(F + off);
  int* counts   = I;
  int* offs     = I + 512;
  int* cursor   = I + 1024;
  int* csr_soff = I + 1536;                  // E2_ entries

  hipMemsetAsync(deg, 0, 512 * sizeof(float), stream);
  hipMemsetAsync(counts, 0, 512 * sizeof(int), stream);
  hipMemsetAsync(y1, 0, 32768 * sizeof(float), stream);

  k_deg_count<<<48, 256, 0, stream>>>(ei, ew, deg, counts);
  k_gnorm<<<48, 256, 0, stream>>>(ei, ew, deg, gnorm);
  k_scan<<<1, 64, 0, stream>>>(counts, offs, cursor);
  k_fill<<<48, 256, 0, stream>>>(ei, gnorm, cursor, csr_soff, csr_g);
  k_wtr<<<240, 256, 0, stream>>>(W_t, WT);
  hipMemcpyAsync(h, x, (size_t)GN_ * 64 * sizeof(float), hipMemcpyDeviceToDevice, stream);

  for (int l = 0; l < 3; ++l){
    k_rowgemm<<<370, 256, 0, stream>>>(h, W_gcn + l * 4096, bufB);
    k_gcn_agg<<<11840, 256, 0, stream>>>(bufB, csr_soff, offs, csr_g, b_gcn + l * 64, bufC);
    k_rowgemm<<<370, 256, 0, stream>>>(bufC, W_gat + l * 4096, bufD);
    k_attn<<<740, 256, 0, stream>>>(bufD, att_s + l * 64, att_d + l * 64, asrc, adst);
    k_alpha<<<740, 256, 0, stream>>>(asrc, adst, csr_soff, offs, alpha, invden);
    k_gat_agg<<<11840, 256, 0, stream>>>(bufD, alpha, invden, csr_soff, offs,
                                         b_gat + l * 64, ln_g + l * 64, ln_b + l * 64, h);
  }

  k_tfuse<<<740, 256, 0, stream>>>(h, WT, b_t, bufD);

  dim3 g1(4, 128);
  k_mlp1<<<g1, 256, 0, stream>>>(bufD, W1, y1);
  k_mlp2<<<128, 64, 0, stream>>>(y1, b1, W2, b2, outp);
}

// Round 9
// 678.676 us; speedup vs baseline: 1.3761x; 1.2195x over previous
//
#include <hip/hip_runtime.h>
#include <hip/hip_bf16.h>

// Problem constants
#define B_   4
#define T_   32
#define N_   370
#define E_   11840
#define E2_  12210          // E_ + N_ self loops
#define H_   64
#define G_   128            // B_*T_
#define GN_  47360          // G_*N_
#define BN_  1480           // B_*N_
#define NH_  23680          // N_*H_
#define ECAP 320            // LDS edge-stage capacity per node (max deg ~60)

__device__ __forceinline__ float gelu_f(float x){
  return 0.5f * x * (1.0f + erff(x * 0.7071067811865475f));
}
__device__ __forceinline__ float wsum64(float v){
  #pragma unroll
  for (int m = 32; m > 0; m >>= 1) v += __shfl_xor(v, m, 64);
  return v;
}
__device__ __forceinline__ float lrelu(float v){ return v > 0.f ? v : 0.2f * v; }

// ---------- edge preprocessing ----------
__global__ void k_deg_count(const int* __restrict__ ei, const float* __restrict__ ew,
                            float* __restrict__ deg, int* __restrict__ counts){
  int e = blockIdx.x * 256 + threadIdx.x;
  if (e >= E2_) return;
  int dst = (e < E_) ? ei[E_ + e] : (e - E_);
  float w = (e < E_) ? ew[e] : 1.0f;
  atomicAdd(&deg[dst], w);
  atomicAdd(&counts[dst], 1);
}

__global__ void k_gnorm(const int* __restrict__ ei, const float* __restrict__ ew,
                        const float* __restrict__ deg, float* __restrict__ gnorm){
  int e = blockIdx.x * 256 + threadIdx.x;
  if (e >= E2_) return;
  int s = (e < E_) ? ei[e] : (e - E_);
  int d = (e < E_) ? ei[E_ + e] : (e - E_);
  float w = (e < E_) ? ew[e] : 1.0f;
  float ds = deg[s] > 0.f ? rsqrtf(deg[s]) : 0.f;
  float dd = deg[d] > 0.f ? rsqrtf(deg[d]) : 0.f;
  gnorm[e] = ds * w * dd;
}

// wave-parallel exclusive scan over counts (one wave)
__global__ void k_scan(const int* __restrict__ counts, int* __restrict__ offs,
                       int* __restrict__ cursor){
  int lane = threadIdx.x;
  int run = 0;
  for (int c0 = 0; c0 < N_; c0 += 64){
    int n = c0 + lane;
    int v = (n < N_) ? counts[n] : 0;
    int s = v;
    #pragma unroll
    for (int m = 1; m < 64; m <<= 1){
      int t = __shfl_up(s, m, 64);
      if (lane >= m) s += t;
    }
    int excl = run + s - v;
    if (n < N_){ offs[n] = excl; cursor[n] = excl; }
    run += __shfl(s, 63, 64);
  }
  if (lane == 0) offs[N_] = run;
}

// stores PRE-SCALED source offset s*64 + packed (soff, gnorm) pairs
__global__ void k_fill(const int* __restrict__ ei, const float* __restrict__ gnorm,
                       int* __restrict__ cursor, int* __restrict__ csr_soff,
                       float* __restrict__ csr_g, int2* __restrict__ epack){
  int e = blockIdx.x * 256 + threadIdx.x;
  if (e >= E2_) return;
  int s = (e < E_) ? ei[e] : (e - E_);
  int d = (e < E_) ? ei[E_ + e] : (e - E_);
  int pos = atomicAdd(&cursor[d], 1);
  csr_soff[pos] = s * 64;
  float gw = gnorm[e];
  csr_g[pos] = gw;
  epack[pos] = make_int2(s * 64, __float_as_int(gw));
}

// transpose temporal-conv weights: WT[l][(ci*5+k)*64 + ho] = W_t[l][ho*320+ci*5+k]
__global__ void k_wtr(const float* __restrict__ Wt, float* __restrict__ WT){
  int i = blockIdx.x * 256 + threadIdx.x;     // 3*20480 exact
  int l = i / 20480, rem = i - l * 20480;
  int ho = rem / 320, j = rem - ho * 320;
  WT[l * 20480 + j * 64 + ho] = Wt[i];
}

// rows x 64 @ 64 x 64 -> rows x 64 ; 64 rows/block, 4x4 register tile
__global__ __launch_bounds__(256) void k_rowgemm(const float* __restrict__ in,
                                                 const float* __restrict__ W,
                                                 float* __restrict__ outp){
  __shared__ float Ws[64 * 64];     // [k][col]
  __shared__ float rsT[64 * 68];    // [k][row], padded
  int tid = threadIdx.x;
  size_t r0 = (size_t)blockIdx.x * 64;
  for (int i = tid; i < 4096; i += 256) Ws[i] = W[i];
  for (int i = tid; i < 4096; i += 256){
    int r = i >> 6, k = i & 63;
    rsT[k * 68 + r] = in[(r0 + r) * 64 + k];
  }
  __syncthreads();
  int c0 = (tid & 15) * 4;
  int rr0 = (tid >> 4) * 4;
  float4 a0 = {0,0,0,0}, a1 = {0,0,0,0}, a2 = {0,0,0,0}, a3 = {0,0,0,0};
  #pragma unroll 4
  for (int k = 0; k < 64; ++k){
    float4 rv = *(const float4*)&rsT[k * 68 + rr0];
    float4 wv = *(const float4*)&Ws[k * 64 + c0];
    a0.x += rv.x*wv.x; a0.y += rv.x*wv.y; a0.z += rv.x*wv.z; a0.w += rv.x*wv.w;
    a1.x += rv.y*wv.x; a1.y += rv.y*wv.y; a1.z += rv.y*wv.z; a1.w += rv.y*wv.w;
    a2.x += rv.z*wv.x; a2.y += rv.z*wv.y; a2.z += rv.z*wv.z; a2.w += rv.z*wv.w;
    a3.x += rv.w*wv.x; a3.y += rv.w*wv.y; a3.z += rv.w*wv.z; a3.w += rv.w*wv.w;
  }
  *(float4*)&outp[(r0 + rr0 + 0) * 64 + c0] = a0;
  *(float4*)&outp[(r0 + rr0 + 1) * 64 + c0] = a1;
  *(float4*)&outp[(r0 + rr0 + 2) * 64 + c0] = a2;
  *(float4*)&outp[(r0 + rr0 + 3) * 64 + c0] = a3;
}

// GCN aggregate v3: block = (node n, graph-group of 4). Edge list staged in LDS
// once per block (shared by the 4 waves); per edge: 1 LDS broadcast + 1 gather.
__global__ __launch_bounds__(256) void k_gcn_agg(const float* __restrict__ hw,
    const int2* __restrict__ epack, const int* __restrict__ offs,
    const int* __restrict__ csr_soff, const float* __restrict__ csr_g,
    const float* __restrict__ b_gcn, float* __restrict__ gout){
  __shared__ int2 eS[ECAP];
  int nb = blockIdx.x;              // 0..11839
  int n = nb % N_;
  int gg = nb / N_;                 // 0..31
  int tid = threadIdx.x;
  int o0 = offs[n], o1 = offs[n + 1];
  int deg = o1 - o0;
  int cap = deg < ECAP ? deg : ECAP;
  for (int i = tid; i < cap; i += 256) eS[i] = epack[o0 + i];
  __syncthreads();
  int wv = tid >> 6, c = tid & 63;
  int g = gg * 4 + wv;
  const float* hwg = hw + (size_t)g * NH_;
  float acc = 0.f;
  int p = 0;
  for (; p + 8 <= cap; p += 8){
    int2 e0 = eS[p+0], e1 = eS[p+1], e2 = eS[p+2], e3 = eS[p+3];
    int2 e4 = eS[p+4], e5 = eS[p+5], e6 = eS[p+6], e7 = eS[p+7];
    float v0 = hwg[e0.x+c], v1 = hwg[e1.x+c], v2 = hwg[e2.x+c], v3 = hwg[e3.x+c];
    float v4 = hwg[e4.x+c], v5 = hwg[e5.x+c], v6 = hwg[e6.x+c], v7 = hwg[e7.x+c];
    acc += __int_as_float(e0.y)*v0 + __int_as_float(e1.y)*v1
         + __int_as_float(e2.y)*v2 + __int_as_float(e3.y)*v3
         + __int_as_float(e4.y)*v4 + __int_as_float(e5.y)*v5
         + __int_as_float(e6.y)*v6 + __int_as_float(e7.y)*v7;
  }
  for (; p < cap; ++p){
    int2 e = eS[p];
    acc += __int_as_float(e.y) * hwg[e.x + c];
  }
  for (int q = cap; q < deg; ++q)       // overflow fallback (deg > ECAP: never expected)
    acc += csr_g[o0+q] * hwg[csr_soff[o0+q] + c];
  acc += b_gcn[c];
  gout[((size_t)g * N_ + n) * 64 + c] = gelu_f(acc);
}

// attention scores per (g,n,head)
__global__ void k_attn(const float* __restrict__ gh, const float* __restrict__ att_s,
                       const float* __restrict__ att_d, float* __restrict__ asrc,
                       float* __restrict__ adst){
  int idx = blockIdx.x * 256 + threadIdx.x;   // GN_*4 exact
  int head = idx & 3;
  int gn = idx >> 2;
  const float* row = gh + (size_t)gn * 64 + head * 16;
  float as = 0.f, ad = 0.f;
  #pragma unroll
  for (int d = 0; d < 16; ++d){
    float v = row[d];
    as += v * att_s[head * 16 + d];
    ad += v * att_d[head * 16 + d];
  }
  asrc[idx] = as;
  adst[idx] = ad;
}

// per (g,n,head): softmax max+denominator over incoming edges;
// writes UNNORMALIZED exp weights alpha[g][p][head] and invden[g][n][head]
__global__ void k_alpha(const float* __restrict__ asrc, const float* __restrict__ adst,
                        const int* __restrict__ csr_soff, const int* __restrict__ offs,
                        float* __restrict__ alpha, float* __restrict__ invden){
  int idx = blockIdx.x * 256 + threadIdx.x;   // (g*N+n)*4+head, GN_*4 exact
  int head = idx & 3;
  int gn = idx >> 2;
  int g = gn / N_, n = gn - g * N_;
  int o0 = offs[n], o1 = offs[n + 1];
  const float* as_g = asrc + (size_t)g * (N_ * 4);
  float adv = adst[idx];
  float m = -1e30f;
  int p = o0;
  for (; p + 4 <= o1; p += 4){
    int sa = csr_soff[p+0] >> 4, sb = csr_soff[p+1] >> 4;
    int sc = csr_soff[p+2] >> 4, sd = csr_soff[p+3] >> 4;
    float va = lrelu(as_g[sa + head] + adv);
    float vb = lrelu(as_g[sb + head] + adv);
    float vc = lrelu(as_g[sc + head] + adv);
    float vd = lrelu(as_g[sd + head] + adv);
    m = fmaxf(m, fmaxf(fmaxf(va, vb), fmaxf(vc, vd)));
  }
  for (; p < o1; ++p)
    m = fmaxf(m, lrelu(as_g[(csr_soff[p] >> 4) + head] + adv));
  float* al_g = alpha + (size_t)g * (E2_ * 4);
  float den = 0.f;
  p = o0;
  for (; p + 4 <= o1; p += 4){
    int sa = csr_soff[p+0] >> 4, sb = csr_soff[p+1] >> 4;
    int sc = csr_soff[p+2] >> 4, sd = csr_soff[p+3] >> 4;
    float ea = __expf(lrelu(as_g[sa + head] + adv) - m);
    float eb = __expf(lrelu(as_g[sb + head] + adv) - m);
    float ec = __expf(lrelu(as_g[sc + head] + adv) - m);
    float ed = __expf(lrelu(as_g[sd + head] + adv) - m);
    den += ea + eb + ec + ed;
    al_g[(p+0)*4 + head] = ea;
    al_g[(p+1)*4 + head] = eb;
    al_g[(p+2)*4 + head] = ec;
    al_g[(p+3)*4 + head] = ed;
  }
  for (; p < o1; ++p){
    float ex = __expf(lrelu(as_g[(csr_soff[p] >> 4) + head] + adv) - m);
    den += ex;
    al_g[p*4 + head] = ex;
  }
  invden[idx] = 1.f / den;
}

// GAT aggregate v3: block = (node n, graph-group of 4); soff staged in LDS;
// alpha read as 16B-line broadcast; epilogue bias+residual+LayerNorm on h.
__global__ __launch_bounds__(256) void k_gat_agg(const float* __restrict__ gh,
    const float* __restrict__ alpha, const float* __restrict__ invden,
    const int* __restrict__ csr_soff, const int* __restrict__ offs,
    const float* __restrict__ b_gat, const float* __restrict__ ln_g,
    const float* __restrict__ ln_b, float* __restrict__ h){
  __shared__ int sS[ECAP];
  int nb = blockIdx.x;
  int n = nb % N_;
  int gg = nb / N_;
  int tid = threadIdx.x;
  int o0 = offs[n], o1 = offs[n + 1];
  int deg = o1 - o0;
  int cap = deg < ECAP ? deg : ECAP;
  for (int i = tid; i < cap; i += 256) sS[i] = csr_soff[o0 + i];
  __syncthreads();
  int wv = tid >> 6, c = tid & 63;
  int g = gg * 4 + wv;
  int head = c >> 4;
  const float* gh_g = gh + (size_t)g * NH_;
  const float* al_g = alpha + (size_t)g * (E2_ * 4) + (size_t)o0 * 4 + head;
  float acc = 0.f;
  int p = 0;
  for (; p + 8 <= cap; p += 8){
    int s0 = sS[p+0], s1 = sS[p+1], s2 = sS[p+2], s3 = sS[p+3];
    int s4 = sS[p+4], s5 = sS[p+5], s6 = sS[p+6], s7 = sS[p+7];
    float a0 = al_g[(p+0)*4], a1 = al_g[(p+1)*4], a2 = al_g[(p+2)*4], a3 = al_g[(p+3)*4];
    float a4 = al_g[(p+4)*4], a5 = al_g[(p+5)*4], a6 = al_g[(p+6)*4], a7 = al_g[(p+7)*4];
    float v0 = gh_g[s0+c], v1 = gh_g[s1+c], v2 = gh_g[s2+c], v3 = gh_g[s3+c];
    float v4 = gh_g[s4+c], v5 = gh_g[s5+c], v6 = gh_g[s6+c], v7 = gh_g[s7+c];
    acc += a0*v0 + a1*v1 + a2*v2 + a3*v3 + a4*v4 + a5*v5 + a6*v6 + a7*v7;
  }
  for (; p < cap; ++p)
    acc += al_g[p*4] * gh_g[sS[p] + c];
  for (int q = cap; q < deg; ++q)
    acc += al_g[q*4] * gh_g[csr_soff[o0+q] + c];
  int gn = g * N_ + n;
  float outv = acc * invden[gn * 4 + head] + b_gat[c];
  size_t hidx = (size_t)gn * 64 + c;
  float r = outv + h[hidx];
  float mu = wsum64(r) * (1.f / 64.f);
  float d = r - mu;
  float var = wsum64(d * d) * (1.f / 64.f);
  h[hidx] = d * rsqrtf(var + 1e-5f) * ln_g[c] + ln_b[c];
}

// Fused temporal: transpose + 3 conv layers + reshape. 2 bn per block,
// 2 waves per bn (t0 = 0/16), 16 t per lane, single in-place buffer per bn.
__global__ __launch_bounds__(256) void k_tfuse(const float* __restrict__ h,
    const float* __restrict__ WT, const float* __restrict__ bt,
    float* __restrict__ z){
  __shared__ float tiles[2][64 * 36];
  int tid = threadIdx.x;
  int wv = tid >> 6, lane = tid & 63;
  int bnl = wv >> 1;
  int t0 = (wv & 1) * 16;
  int bn = blockIdx.x * 2 + bnl;
  int b = bn / N_, n = bn - b * N_;
  for (int i = tid; i < 2 * 2304; i += 256) ((float*)tiles)[i] = 0.f;
  __syncthreads();
  {
    float* xa = tiles[bnl];
    for (int i = (wv & 1) * 64 + lane; i < 2048; i += 128){
      int t = i >> 6, ch = i & 63;
      xa[ch * 36 + 2 + t] = h[((size_t)(b * T_ + t) * N_ + n) * 64 + ch];
    }
  }
  __syncthreads();
  int ho = lane;
  float* cur = tiles[bnl];
  #pragma unroll
  for (int l = 0; l < 3; ++l){
    const float* wl = WT + l * 20480 + ho;
    float bv = bt[l * 64 + ho];
    float acc[16];
    #pragma unroll
    for (int r = 0; r < 16; ++r) acc[r] = bv;
    for (int ci = 0; ci < 64; ++ci){
      const float* xr = &cur[ci * 36 + t0];   // xr[q] = x[ci][t0+q-2], q=0..19
      float4 x0 = *(const float4*)&xr[0];
      float4 x1 = *(const float4*)&xr[4];
      float4 x2 = *(const float4*)&xr[8];
      float4 x3 = *(const float4*)&xr[12];
      float4 x4 = *(const float4*)&xr[16];
      float xw[20] = {x0.x,x0.y,x0.z,x0.w, x1.x,x1.y,x1.z,x1.w,
                      x2.x,x2.y,x2.z,x2.w, x3.x,x3.y,x3.z,x3.w,
                      x4.x,x4.y,x4.z,x4.w};
      const float* wp = wl + ci * 320;        // (ci*5+k)*64 + ho
      #pragma unroll
      for (int k = 0; k < 5; ++k){
        float w = wp[k * 64];
        #pragma unroll
        for (int r = 0; r < 16; ++r) acc[r] += xw[r + k] * w;
      }
    }
    __syncthreads();     // all reads of cur done
    #pragma unroll
    for (int r = 0; r < 16; ++r){
      int ti = t0 + r;
      cur[ho * 36 + 2 + ti] = gelu_f(acc[r]) + cur[ho * 36 + 2 + ti];
    }
    __syncthreads();     // writes visible before next layer reads
  }
  for (int i = (wv & 1) * 64 + lane; i < 2048; i += 128){
    int t = i >> 6, ch = i & 63;
    z[(size_t)(b * T_ + t) * NH_ + n * 64 + ch] = cur[ch * 36 + 2 + t];
  }
}

// MLP layer 1: grid (4 rowgroups = b, 128 kchunks of 185);
// each thread: 8 rows x 4 cols (32 FMA per W1 float4 load)
__global__ __launch_bounds__(256) void k_mlp1(const float* __restrict__ z,
    const float* __restrict__ W1, float* __restrict__ y1){
  __shared__ float zs[185 * 36];    // [j][r], r=0..31, stride 36
  int b = blockIdx.x;               // 0..3
  int kc = blockIdx.y;              // 0..127
  int base = kc * 185;
  int tid = threadIdx.x;
  for (int i = tid; i < 185 * 32; i += 256){
    int r = i / 185, j = i - r * 185;
    zs[j * 36 + r] = z[(size_t)(b * T_ + r) * NH_ + base + j];
  }
  __syncthreads();
  int r0 = (tid >> 6) * 8;
  int c0 = (tid & 63) * 4;
  float4 acc[8];
  #pragma unroll
  for (int r = 0; r < 8; ++r) acc[r] = (float4){0,0,0,0};
  const float* wbase = W1 + (size_t)base * 256 + c0;
  #pragma unroll 4
  for (int j = 0; j < 185; ++j){
    float4 wv = *(const float4*)&wbase[(size_t)j * 256];
    float4 za = *(const float4*)&zs[j * 36 + r0];
    float4 zb = *(const float4*)&zs[j * 36 + r0 + 4];
    float zv[8] = {za.x, za.y, za.z, za.w, zb.x, zb.y, zb.z, zb.w};
    #pragma unroll
    for (int q = 0; q < 8; ++q){
      acc[q].x += zv[q]*wv.x; acc[q].y += zv[q]*wv.y;
      acc[q].z += zv[q]*wv.z; acc[q].w += zv[q]*wv.w;
    }
  }
  #pragma unroll
  for (int rr = 0; rr < 8; ++rr){
    int row = b * T_ + r0 + rr;
    float* yp = &y1[(size_t)row * 256 + c0];
    atomicAdd(&yp[0], acc[rr].x);
    atomicAdd(&yp[1], acc[rr].y);
    atomicAdd(&yp[2], acc[rr].z);
    atomicAdd(&yp[3], acc[rr].w);
  }
}

// MLP layer 2: out[128,64] = gelu(y1+b1) @ W2 + b2
__global__ __launch_bounds__(64) void k_mlp2(const float* __restrict__ y1,
    const float* __restrict__ b1, const float* __restrict__ W2,
    const float* __restrict__ b2, float* __restrict__ outp){
  __shared__ float a[256];
  int row = blockIdx.x, tid = threadIdx.x;
  for (int i = tid; i < 256; i += 64) a[i] = gelu_f(y1[(size_t)row * 256 + i] + b1[i]);
  __syncthreads();
  float acc = b2[tid];
  for (int i = 0; i < 256; ++i) acc += a[i] * W2[i * 64 + tid];
  outp[row * 64 + tid] = acc;
}

extern "C" void kernel_launch(void* const* d_in, const int* in_sizes, int n_in,
                              void* d_out, int out_size, void* d_ws, size_t ws_size,
                              hipStream_t stream){
  const float* x     = (const float*)d_in[0];
  const int*   ei    = (const int*)  d_in[1];
  const float* ew    = (const float*)d_in[2];
  const float* W_gcn = (const float*)d_in[3];
  const float* b_gcn = (const float*)d_in[4];
  const float* W_gat = (const float*)d_in[5];
  const float* att_s = (const float*)d_in[6];
  const float* att_d = (const float*)d_in[7];
  const float* b_gat = (const float*)d_in[8];
  const float* W_t   = (const float*)d_in[9];
  const float* b_t   = (const float*)d_in[10];
  const float* ln_g  = (const float*)d_in[11];
  const float* ln_b  = (const float*)d_in[12];
  const float* W1    = (const float*)d_in[13];
  const float* b1    = (const float*)d_in[14];
  const float* W2    = (const float*)d_in[15];
  const float* b2    = (const float*)d_in[16];
  float* outp = (float*)d_out;

  float* F = (float*)d_ws;
  size_t off = 0;
  float* deg    = F + off; off += 512;
  float* gnorm  = F + off; off += 12288;
  float* csr_g  = F + off; off += 12288;
  float* asrc   = F + off; off += 189440;
  float* adst   = F + off; off += 189440;
  float* invden = F + off; off += 189440;
  float* y1     = F + off; off += 32768;
  float* WT     = F + off; off += 61440;     // transposed temporal weights
  float* h      = F + off; off += 3031040;
  float* bufB   = F + off; off += 3031040;   // hw
  float* bufC   = F + off; off += 3031040;   // g
  float* bufD   = F + off; off += 3031040;   // gh / z
  float* alpha  = F + off; off += (size_t)G_ * E2_ * 4;   // 6,251,520
  int* I        = (int*)(F + off);
  int* counts   = I;
  int* offs     = I + 512;
  int* cursor   = I + 1024;
  int* csr_soff = I + 1536;                  // E2_ entries (12288 slot)
  int2* epack   = (int2*)(I + 13824);        // E2_ int2 entries

  hipMemsetAsync(deg, 0, 512 * sizeof(float), stream);
  hipMemsetAsync(counts, 0, 512 * sizeof(int), stream);
  hipMemsetAsync(y1, 0, 32768 * sizeof(float), stream);

  k_deg_count<<<48, 256, 0, stream>>>(ei, ew, deg, counts);
  k_gnorm<<<48, 256, 0, stream>>>(ei, ew, deg, gnorm);
  k_scan<<<1, 64, 0, stream>>>(counts, offs, cursor);
  k_fill<<<48, 256, 0, stream>>>(ei, gnorm, cursor, csr_soff, csr_g, epack);
  k_wtr<<<240, 256, 0, stream>>>(W_t, WT);
  hipMemcpyAsync(h, x, (size_t)GN_ * 64 * sizeof(float), hipMemcpyDeviceToDevice, stream);

  for (int l = 0; l < 3; ++l){
    k_rowgemm<<<740, 256, 0, stream>>>(h, W_gcn + l * 4096, bufB);
    k_gcn_agg<<<11840, 256, 0, stream>>>(bufB, epack, offs, csr_soff, csr_g,
                                         b_gcn + l * 64, bufC);
    k_rowgemm<<<740, 256, 0, stream>>>(bufC, W_gat + l * 4096, bufD);
    k_attn<<<740, 256, 0, stream>>>(bufD, att_s + l * 64, att_d + l * 64, asrc, adst);
    k_alpha<<<740, 256, 0, stream>>>(asrc, adst, csr_soff, offs, alpha, invden);
    k_gat_agg<<<11840, 256, 0, stream>>>(bufD, alpha, invden, csr_soff, offs,
                                         b_gat + l * 64, ln_g + l * 64, ln_b + l * 64, h);
  }

  k_tfuse<<<740, 256, 0, stream>>>(h, WT, b_t, bufD);

  dim3 g1(4, 128);
  k_mlp1<<<g1, 256, 0, stream>>>(bufD, W1, y1);
  k_mlp2<<<128, 64, 0, stream>>>(y1, b1, W2, b2, outp);
}